// Round 1
// baseline (455.154 us; speedup 1.0000x reference)
//
#include <hip/hip_runtime.h>
#include <hip/hip_bf16.h>

typedef __attribute__((ext_vector_type(8))) __bf16 bf16x8;
typedef __attribute__((ext_vector_type(4))) float f32x4;

#define B_   16
#define C_   128
#define DIM  24
#define F_   128
#define OD   22
#define OS   (OD*OD*OD)        // 10648
#define SPB  (DIM*DIM*DIM)     // 13824 spatial per (b)
#define K_   3456              // 128*27
#define M_   (B_*OS)           // 170368
#define OUTN (B_*F_*OS)        // 21807104

// ---------------- async global->LDS (16B per lane, wave-uniform LDS base) ---
__device__ __forceinline__ void async16(const void* g, void* l) {
  __builtin_amdgcn_global_load_lds(
      (const __attribute__((address_space(1))) unsigned int*)g,
      (__attribute__((address_space(3))) unsigned int*)l, 16, 0, 0);
}

// ---------------- kernel 1: xs -> channels-last bf16 xt, plus sum_c x^2 -----
__global__ void prep_x(const float* __restrict__ xs, __bf16* __restrict__ xt,
                       float* __restrict__ s1) {
  __shared__ float tile[C_ * DIM];           // 12 KB
  const int blk = blockIdx.x;                // (b*24+z)*24+y, 9216 blocks
  const int y = blk % DIM;
  const int t2 = blk / DIM;
  const int z = t2 % DIM;
  const int b = t2 / DIM;
  const float* src = xs + (size_t)b * C_ * SPB + z * (DIM * DIM) + y * DIM;
  for (int it = 0; it < (C_ * DIM) / 256; ++it) {
    int idx = it * 256 + threadIdx.x;
    int c = idx / DIM, x = idx - c * DIM;
    tile[c * DIM + x] = src[(size_t)c * SPB + x];
  }
  __syncthreads();
  size_t obase = (size_t)blk * DIM * C_;
  for (int it = 0; it < (C_ * DIM) / 256; ++it) {
    int idx = it * 256 + threadIdx.x;
    int c = idx & (C_ - 1), x = idx >> 7;
    xt[obase + (size_t)x * C_ + c] = (__bf16)tile[c * DIM + x];
  }
  if (threadIdx.x < DIM) {
    float s = 0.f;
    for (int c = 0; c < C_; ++c) {
      float v = tile[c * DIM + threadIdx.x];
      s += v * v;
    }
    s1[blk * DIM + threadIdx.x] = s;
  }
}

// ---------------- kernel 2: weights -> Wt[f][off*128+c] bf16, plus ||p||^2 --
__global__ void prep_w(const float* __restrict__ fv, __bf16* __restrict__ Wt,
                       float* __restrict__ psq) {
  const int f = blockIdx.x;                  // 128 blocks
  const float* src = fv + (size_t)f * K_;
  float part = 0.f;
  for (int idx = threadIdx.x; idx < K_; idx += 256) {
    int c = idx & 127, off = idx >> 7;       // k = off*128 + c
    float v = src[c * 27 + off];
    part += v * v;
    Wt[(size_t)f * K_ + idx] = (__bf16)v;
  }
  for (int o = 32; o > 0; o >>= 1) part += __shfl_down(part, o, 64);
  __shared__ float red[4];
  int w = threadIdx.x >> 6, l = threadIdx.x & 63;
  if (l == 0) red[w] = part;
  __syncthreads();
  if (threadIdx.x == 0) psq[f] = red[0] + red[1] + red[2] + red[3];
}

// ---------------- kernel 3: 3x3x3 valid sum-pool of s1 ----------------------
__global__ void pool_sq(const float* __restrict__ s1, float* __restrict__ xsq) {
  int i = blockIdx.x * 256 + threadIdx.x;
  if (i >= M_) return;
  int ow = i % OD;
  int t = i / OD;
  int oh = t % OD; t /= OD;
  int od = t % OD;
  int b = t / OD;
  const float* p = s1 + ((b * DIM + od) * DIM + oh) * DIM + ow;
  float s = 0.f;
#pragma unroll
  for (int dz = 0; dz < 3; ++dz)
#pragma unroll
    for (int dy = 0; dy < 3; ++dy)
#pragma unroll
      for (int dx = 0; dx < 3; ++dx)
        s += p[dz * 576 + dy * 24 + dx];
  xsq[i] = s;
}

// ---------------- kernel 4: implicit-GEMM MFMA + fused L2 epilogue ----------
// A-operand = weights Wt[128 f][K], B-operand = patches (gathered), tile
// 128f x 128m, BK=64 (one kernel-offset half: k = off*128 + c0 + [0,64)).
__global__ __launch_bounds__(256) void l2gemm(
    const __bf16* __restrict__ xt, const __bf16* __restrict__ Wt,
    const float* __restrict__ xsq, const float* __restrict__ psq,
    float* __restrict__ out) {
  __shared__ __align__(16) __bf16 Wl[128 * 64];   // 16 KB
  __shared__ __align__(16) __bf16 Pl[128 * 64];   // 16 KB
  const int t = threadIdx.x;
  const int l = t & 63, w = t >> 6;
  const int quad = l >> 4, lan = l & 15;
  const int e = t & 7, r0 = t >> 3;     // staging: chunk e (16B) of row r0+32p
  const int mt = blockIdx.x;

  // spatial base (element index into xt / 128ch) for the 4 staged patch rows
  int sb[4];
#pragma unroll
  for (int p = 0; p < 4; ++p) {
    int m = mt * 128 + r0 + 32 * p;
    int b = m / OS;
    int s = m - b * OS;
    int od = s / (OD * OD);
    int s2 = s - od * (OD * OD);
    int oh = s2 / OD;
    int ow = s2 - oh * OD;
    sb[p] = b * SPB + od * 576 + oh * 24 + ow;
  }

  f32x4 acc[4][4];
#pragma unroll
  for (int i = 0; i < 4; ++i)
#pragma unroll
    for (int n = 0; n < 4; ++n) acc[i][n] = (f32x4){0.f, 0.f, 0.f, 0.f};

  const int wm = (w >> 1) * 64;   // f-offset of this wave's 64x64 subtile
  const int wn = (w & 1) * 64;    // patch-offset
  __bf16* wl_base = &Wl[(w * 8) * 64];
  __bf16* pl_base = &Pl[(w * 8) * 64];

#pragma unroll 1
  for (int kt = 0; kt < 54; ++kt) {
    int off = kt >> 1;
    int dz = off / 9;
    int rem = off - dz * 9;
    int dy = rem / 3;
    int dx = rem - dy * 3;
    int doff = dz * 576 + dy * 24 + dx;
    int c0 = (kt & 1) << 6;
    __syncthreads();   // previous tile's compute done before overwrite
#pragma unroll
    for (int p = 0; p < 4; ++p) {
      const __bf16* gp = xt + (((size_t)(sb[p] + doff)) << 7) + c0 + e * 8;
      async16(gp, pl_base + (size_t)(32 * p) * 64);
      const __bf16* gw = Wt + (size_t)(r0 + 32 * p) * K_ + kt * 64 + e * 8;
      async16(gw, wl_base + (size_t)(32 * p) * 64);
    }
    __syncthreads();   // compiler drains vmcnt before s_barrier
#pragma unroll
    for (int kk = 0; kk < 2; ++kk) {
      bf16x8 a[4], bb[4];
#pragma unroll
      for (int i = 0; i < 4; ++i)
        a[i] = *(const bf16x8*)&Wl[(wm + i * 16 + lan) * 64 + kk * 32 + quad * 8];
#pragma unroll
      for (int n = 0; n < 4; ++n)
        bb[n] = *(const bf16x8*)&Pl[(wn + n * 16 + lan) * 64 + kk * 32 + quad * 8];
#pragma unroll
      for (int i = 0; i < 4; ++i)
#pragma unroll
        for (int n = 0; n < 4; ++n)
          acc[i][n] = __builtin_amdgcn_mfma_f32_16x16x32_bf16(a[i], bb[n],
                                                              acc[i][n], 0, 0, 0);
    }
  }

  // epilogue: out[b][f][s] = sqrt(|xsq + psq - 2*dot| + eps)
  int mb[4];
  float xv[4];
#pragma unroll
  for (int n = 0; n < 4; ++n) {
    int m = mt * 128 + wn + n * 16 + lan;
    int b = m / OS;
    int s = m - b * OS;
    mb[n] = b * (F_ * OS) + s;
    xv[n] = xsq[m];
  }
#pragma unroll
  for (int i = 0; i < 4; ++i) {
#pragma unroll
    for (int r = 0; r < 4; ++r) {
      int f = wm + i * 16 + quad * 4 + r;
      float pq = psq[f];
#pragma unroll
      for (int n = 0; n < 4; ++n) {
        float d = xv[n] + pq - 2.0f * acc[i][n][r];
        out[mb[n] + f * OS] = sqrtf(fabsf(d) + 1e-14f);
      }
    }
  }
}

// ---------------- fallback: direct fp32 conv (only if ws too small) ---------
__global__ void l2conv_direct(const float* __restrict__ xs,
                              const float* __restrict__ fv,
                              float* __restrict__ out) {
  int i = blockIdx.x * 256 + threadIdx.x;
  if (i >= OUTN) return;
  int s = i % OS;
  int t2 = i / OS;
  int f = t2 & 127;
  int b = t2 >> 7;
  int od = s / (OD * OD);
  int s2 = s - od * (OD * OD);
  int oh = s2 / OD;
  int ow = s2 - oh * OD;
  const float* xp = xs + (size_t)b * C_ * SPB + od * 576 + oh * 24 + ow;
  const float* wp = fv + (size_t)f * K_;
  float dot = 0.f, xq = 0.f, pq = 0.f;
  for (int c = 0; c < C_; ++c) {
    const float* xpc = xp + (size_t)c * SPB;
    const float* wpc = wp + c * 27;
#pragma unroll
    for (int o = 0; o < 27; ++o) {
      int dz = o / 9;
      int ry = o - dz * 9;
      int dy = ry / 3;
      int dx = ry - dy * 3;
      float xv = xpc[dz * 576 + dy * 24 + dx];
      float wv = wpc[o];
      dot += xv * wv;
      xq += xv * xv;
      pq += wv * wv;
    }
  }
  out[i] = sqrtf(fabsf(xq + pq - 2.f * dot) + 1e-14f);
}

// ---------------- launch ----------------------------------------------------
extern "C" void kernel_launch(void* const* d_in, const int* in_sizes, int n_in,
                              void* d_out, int out_size, void* d_ws,
                              size_t ws_size, hipStream_t stream) {
  const float* xs = (const float*)d_in[0];
  const float* fv = (const float*)d_in[1];
  float* out = (float*)d_out;

  const size_t xt_b  = (size_t)B_ * SPB * C_ * 2;   // 56,623,104
  const size_t wt_b  = (size_t)F_ * K_ * 2;         //    884,736
  const size_t s1_b  = (size_t)B_ * SPB * 4;        //    884,736
  const size_t xsq_b = (size_t)M_ * 4;              //    681,472
  const size_t psq_b = 512;
  if (ws_size < xt_b + wt_b + s1_b + xsq_b + psq_b) {
    l2conv_direct<<<(OUTN + 255) / 256, 256, 0, stream>>>(xs, fv, out);
    return;
  }
  char* p = (char*)d_ws;
  __bf16* xt = (__bf16*)p;          p += xt_b;
  __bf16* Wt = (__bf16*)p;          p += wt_b;
  float*  s1 = (float*)p;           p += s1_b;
  float*  xsq = (float*)p;          p += xsq_b;
  float*  psq = (float*)p;

  prep_x<<<B_ * DIM * DIM, 256, 0, stream>>>(xs, xt, s1);
  prep_w<<<F_, 256, 0, stream>>>(fv, Wt, psq);
  pool_sq<<<(M_ + 255) / 256, 256, 0, stream>>>(s1, xsq);
  l2gemm<<<M_ / 128, 256, 0, stream>>>(xt, Wt, xsq, psq, out);
}

// Round 2
// 410.115 us; speedup vs baseline: 1.1098x; 1.1098x over previous
//
#include <hip/hip_runtime.h>
#include <hip/hip_bf16.h>

typedef __attribute__((ext_vector_type(8))) __bf16 bf16x8;
typedef __attribute__((ext_vector_type(2))) __bf16 bf16x2;
typedef __attribute__((ext_vector_type(4))) float f32x4;

#define B_   16
#define C_   128
#define DIM  24
#define F_   128
#define OD   22
#define OS   (OD*OD*OD)        // 10648
#define SPB  (DIM*DIM*DIM)     // 13824 spatial per (b)
#define K_   3456              // 128*27
#define M_   (B_*OS)           // 170368
#define OUTN (B_*F_*OS)        // 21807104

// ---------------- async global->LDS (16B per lane, wave-uniform LDS base) ---
__device__ __forceinline__ void async16(const void* g, void* l) {
  __builtin_amdgcn_global_load_lds(
      (const __attribute__((address_space(1))) unsigned int*)g,
      (__attribute__((address_space(3))) unsigned int*)l, 16, 0, 0);
}

// ---------------- kernel 1: xs -> channels-last bf16 xt, plus sum_c x^2 -----
// Block = (b, z, y-quad): reads 384B-contiguous runs per channel (4 y-rows),
// LDS tile [128c][96pos] padded to 97 to break bank-stride-0 conflicts.
__global__ __launch_bounds__(256) void prep_x(const float* __restrict__ xs,
                                              __bf16* __restrict__ xt,
                                              float* __restrict__ s1) {
  __shared__ float tile[C_ * 97];            // 49.7 KB
  __shared__ float red[192];
  const int blk = blockIdx.x;                // (b*24+z)*6+yg, 2304 blocks
  const int yg = blk % 6;
  const int t2 = blk / 6;
  const int z = t2 % DIM;
  const int b = t2 / DIM;
  const int t = threadIdx.x;
  const float* src = xs + (size_t)b * C_ * SPB + z * (DIM * DIM) + yg * 96;
  // load: 128c x 24 float4 (96 contiguous floats per c)
  for (int it = 0; it < 12; ++it) {
    int idx = it * 256 + t;
    int c = idx / 24, f4 = idx - c * 24;
    const float4 v = *(const float4*)(src + (size_t)c * SPB + f4 * 4);
    float* d = &tile[c * 97 + f4 * 4];
    d[0] = v.x; d[1] = v.y; d[2] = v.z; d[3] = v.w;
  }
  __syncthreads();
  // store transposed bf16: [96 pos][128 c], 2 c per thread (4B stores)
  size_t obase = ((size_t)b * SPB + z * (DIM * DIM) + yg * 96) * C_;
  for (int it = 0; it < 24; ++it) {
    int idx = it * 256 + t;
    int c2 = idx & 63, x = idx >> 6;
    bf16x2 v;
    v[0] = (__bf16)tile[(2 * c2) * 97 + x];
    v[1] = (__bf16)tile[(2 * c2 + 1) * 97 + x];
    *(bf16x2*)&xt[obase + (size_t)x * C_ + 2 * c2] = v;
  }
  // s1: sum_c x^2 for the 96 positions, 2-way split over c
  if (t < 192) {
    int g = t / 96, p = t - g * 96;
    float s = 0.f;
    for (int c = g; c < C_; c += 2) {
      float v = tile[c * 97 + p];
      s += v * v;
    }
    red[g * 96 + p] = s;
  }
  __syncthreads();
  if (t < 96)
    s1[((size_t)b * SPB + z * (DIM * DIM) + yg * 96) + t] = red[t] + red[96 + t];
}

// ---------------- kernel 2: weights -> Wt[f][off*128+c] bf16, plus ||p||^2 --
__global__ void prep_w(const float* __restrict__ fv, __bf16* __restrict__ Wt,
                       float* __restrict__ psq) {
  __shared__ float tile[K_];                 // 13.8 KB
  const int f = blockIdx.x;                  // 128 blocks
  const float* src = fv + (size_t)f * K_;
  float part = 0.f;
  for (int idx = threadIdx.x; idx < K_; idx += 256) {
    float v = src[idx];                      // coalesced
    tile[idx] = v;
    part += v * v;
  }
  __syncthreads();
  for (int idx = threadIdx.x; idx < K_; idx += 256) {
    int c = idx & 127, off = idx >> 7;       // k = off*128 + c
    Wt[(size_t)f * K_ + idx] = (__bf16)tile[c * 27 + off];  // 27co32 coprime: no conflict
  }
  for (int o = 32; o > 0; o >>= 1) part += __shfl_down(part, o, 64);
  __shared__ float red[4];
  int w = threadIdx.x >> 6, l = threadIdx.x & 63;
  if (l == 0) red[w] = part;
  __syncthreads();
  if (threadIdx.x == 0) psq[f] = red[0] + red[1] + red[2] + red[3];
}

// ---------------- kernel 3: 3x3x3 valid sum-pool of s1 ----------------------
__global__ void pool_sq(const float* __restrict__ s1, float* __restrict__ xsq) {
  int i = blockIdx.x * 256 + threadIdx.x;
  if (i >= M_) return;
  int ow = i % OD;
  int t = i / OD;
  int oh = t % OD; t /= OD;
  int od = t % OD;
  int b = t / OD;
  const float* p = s1 + ((b * DIM + od) * DIM + oh) * DIM + ow;
  float s = 0.f;
#pragma unroll
  for (int dz = 0; dz < 3; ++dz)
#pragma unroll
    for (int dy = 0; dy < 3; ++dy)
#pragma unroll
      for (int dx = 0; dx < 3; ++dx)
        s += p[dz * 576 + dy * 24 + dx];
  xsq[i] = s;
}

// ---------------- kernel 4: implicit-GEMM MFMA + fused L2 epilogue ----------
// A = weights Wt[128 f][K], B = patches (gathered), tile 128f x 128m, BK=64.
// LDS rows are 64 bf16 = exactly 32 banks, so chunk positions are XOR-swizzled
// by (row&7): chunk e of row r lives at LDS slot e^(r&7). Staging permutes the
// GLOBAL source chunk (LDS dest must stay lane-contiguous for global_load_lds);
// reads apply the same XOR. Kills the 5.5e7 bank-conflict cycles of R1.
__global__ __launch_bounds__(256) void l2gemm(
    const __bf16* __restrict__ xt, const __bf16* __restrict__ Wt,
    const float* __restrict__ xsq, const float* __restrict__ psq,
    float* __restrict__ out) {
  __shared__ __align__(16) __bf16 Wl[128 * 64];   // 16 KB
  __shared__ __align__(16) __bf16 Pl[128 * 64];   // 16 KB
  const int t = threadIdx.x;
  const int l = t & 63, w = t >> 6;
  const int quad = l >> 4, lan = l & 15;
  const int e = t & 7, r0 = t >> 3;     // staging: chunk e (16B) of row r0+32p
  const int esw = (e ^ (r0 & 7)) * 8;   // XOR-swizzled source chunk (bf16 units)
  const int mt = blockIdx.x;

  // spatial base (element index into xt / 128ch) for the 4 staged patch rows
  int sb[4];
#pragma unroll
  for (int p = 0; p < 4; ++p) {
    int m = mt * 128 + r0 + 32 * p;
    int b = m / OS;
    int s = m - b * OS;
    int od = s / (OD * OD);
    int s2 = s - od * (OD * OD);
    int oh = s2 / OD;
    int ow = s2 - oh * OD;
    sb[p] = b * SPB + od * 576 + oh * 24 + ow;
  }

  f32x4 acc[4][4];
#pragma unroll
  for (int i = 0; i < 4; ++i)
#pragma unroll
    for (int n = 0; n < 4; ++n) acc[i][n] = (f32x4){0.f, 0.f, 0.f, 0.f};

  const int wm = (w >> 1) * 64;   // f-offset of this wave's 64x64 subtile
  const int wn = (w & 1) * 64;    // patch-offset
  __bf16* wl_base = &Wl[(w * 8) * 64];
  __bf16* pl_base = &Pl[(w * 8) * 64];

#pragma unroll 1
  for (int kt = 0; kt < 54; ++kt) {
    int off = kt >> 1;
    int dz = off / 9;
    int rem = off - dz * 9;
    int dy = rem / 3;
    int dx = rem - dy * 3;
    int doff = dz * 576 + dy * 24 + dx;
    int c0 = (kt & 1) << 6;
    __syncthreads();   // previous tile's compute done before overwrite
#pragma unroll
    for (int p = 0; p < 4; ++p) {
      const __bf16* gp = xt + (((size_t)(sb[p] + doff)) << 7) + c0 + esw;
      async16(gp, pl_base + (size_t)(32 * p) * 64);
      const __bf16* gw = Wt + (size_t)(r0 + 32 * p) * K_ + kt * 64 + esw;
      async16(gw, wl_base + (size_t)(32 * p) * 64);
    }
    __syncthreads();   // compiler drains vmcnt before s_barrier
#pragma unroll
    for (int kk = 0; kk < 2; ++kk) {
      bf16x8 a[4], bb[4];
      const int swz = (((kk * 4 + quad) ^ (lan & 7))) * 8;  // read-side XOR
#pragma unroll
      for (int i = 0; i < 4; ++i)
        a[i] = *(const bf16x8*)&Wl[(wm + i * 16 + lan) * 64 + swz];
#pragma unroll
      for (int n = 0; n < 4; ++n)
        bb[n] = *(const bf16x8*)&Pl[(wn + n * 16 + lan) * 64 + swz];
#pragma unroll
      for (int i = 0; i < 4; ++i)
#pragma unroll
        for (int n = 0; n < 4; ++n)
          acc[i][n] = __builtin_amdgcn_mfma_f32_16x16x32_bf16(a[i], bb[n],
                                                              acc[i][n], 0, 0, 0);
    }
  }

  // epilogue: out[b][f][s] = sqrt(|xsq + psq - 2*dot| + eps)
  int mb[4];
  float xv[4];
#pragma unroll
  for (int n = 0; n < 4; ++n) {
    int m = mt * 128 + wn + n * 16 + lan;
    int b = m / OS;
    int s = m - b * OS;
    mb[n] = b * (F_ * OS) + s;
    xv[n] = xsq[m];
  }
#pragma unroll
  for (int i = 0; i < 4; ++i) {
#pragma unroll
    for (int r = 0; r < 4; ++r) {
      int f = wm + i * 16 + quad * 4 + r;
      float pq = psq[f];
#pragma unroll
      for (int n = 0; n < 4; ++n) {
        float d = xv[n] + pq - 2.0f * acc[i][n][r];
        out[mb[n] + f * OS] = sqrtf(fabsf(d) + 1e-14f);
      }
    }
  }
}

// ---------------- fallback: direct fp32 conv (only if ws too small) ---------
__global__ void l2conv_direct(const float* __restrict__ xs,
                              const float* __restrict__ fv,
                              float* __restrict__ out) {
  int i = blockIdx.x * 256 + threadIdx.x;
  if (i >= OUTN) return;
  int s = i % OS;
  int t2 = i / OS;
  int f = t2 & 127;
  int b = t2 >> 7;
  int od = s / (OD * OD);
  int s2 = s - od * (OD * OD);
  int oh = s2 / OD;
  int ow = s2 - oh * OD;
  const float* xp = xs + (size_t)b * C_ * SPB + od * 576 + oh * 24 + ow;
  const float* wp = fv + (size_t)f * K_;
  float dot = 0.f, xq = 0.f, pq = 0.f;
  for (int c = 0; c < C_; ++c) {
    const float* xpc = xp + (size_t)c * SPB;
    const float* wpc = wp + c * 27;
#pragma unroll
    for (int o = 0; o < 27; ++o) {
      int dz = o / 9;
      int ry = o - dz * 9;
      int dy = ry / 3;
      int dx = ry - dy * 3;
      float xv = xpc[dz * 576 + dy * 24 + dx];
      float wv = wpc[o];
      dot += xv * wv;
      xq += xv * xv;
      pq += wv * wv;
    }
  }
  out[i] = sqrtf(fabsf(xq + pq - 2.f * dot) + 1e-14f);
}

// ---------------- launch ----------------------------------------------------
extern "C" void kernel_launch(void* const* d_in, const int* in_sizes, int n_in,
                              void* d_out, int out_size, void* d_ws,
                              size_t ws_size, hipStream_t stream) {
  const float* xs = (const float*)d_in[0];
  const float* fv = (const float*)d_in[1];
  float* out = (float*)d_out;

  const size_t xt_b  = (size_t)B_ * SPB * C_ * 2;   // 56,623,104
  const size_t wt_b  = (size_t)F_ * K_ * 2;         //    884,736
  const size_t s1_b  = (size_t)B_ * SPB * 4;        //    884,736
  const size_t xsq_b = (size_t)M_ * 4;              //    681,472
  const size_t psq_b = 512;
  if (ws_size < xt_b + wt_b + s1_b + xsq_b + psq_b) {
    l2conv_direct<<<(OUTN + 255) / 256, 256, 0, stream>>>(xs, fv, out);
    return;
  }
  char* p = (char*)d_ws;
  __bf16* xt = (__bf16*)p;          p += xt_b;
  __bf16* Wt = (__bf16*)p;          p += wt_b;
  float*  s1 = (float*)p;           p += s1_b;
  float*  xsq = (float*)p;          p += xsq_b;
  float*  psq = (float*)p;

  prep_x<<<B_ * DIM * DIM / 4, 256, 0, stream>>>(xs, xt, s1);
  prep_w<<<F_, 256, 0, stream>>>(fv, Wt, psq);
  pool_sq<<<(M_ + 255) / 256, 256, 0, stream>>>(s1, xsq);
  l2gemm<<<M_ / 128, 256, 0, stream>>>(xt, Wt, xsq, psq, out);
}